// Round 5
// baseline (8004.384 us; speedup 1.0000x reference)
//
#include <hip/hip_runtime.h>

typedef unsigned short ushort;
typedef unsigned int uint;
typedef __bf16 bf16x8 __attribute__((ext_vector_type(8)));
typedef ushort ushort8 __attribute__((ext_vector_type(8)));
typedef float f32x4 __attribute__((ext_vector_type(4)));

#define Z4 f32x4{0.f, 0.f, 0.f, 0.f}

__device__ __forceinline__ f32x4 mfma16(bf16x8 a, bf16x8 b, f32x4 c) {
    return __builtin_amdgcn_mfma_f32_16x16x32_bf16(a, b, c, 0, 0, 0);
}

__device__ __forceinline__ ushort f2bf(float f) {  // RNE
    union { float f; uint u; } v; v.f = f;
    uint u = v.u;
    uint r = (u + 0x7fffu + ((u >> 16) & 1u)) >> 16;
    return (ushort)r;
}
__device__ __forceinline__ float sigmoidf_(float x) { return 1.f / (1.f + __expf(-x)); }
__device__ __forceinline__ float tanhf_(float x) {
    float e = __expf(2.f * x);
    return 1.f - 2.f / (e + 1.f);
}

// ---------------------------------------------------------------------------
// Weight pre-pack into MFMA-B fragment-major layout.
// For logical B matrix [N,K] (bf16 source value src(n,k)), fragment
// f = ntile*(K/32) + kf holds, contiguously per lane l (0..63):
//   elems j=0..7:  src(ntile*16 + (l&15), kf*32 + (l>>4)*8 + j)
// One fragment = 64 lanes * 16 B = 1024 B contiguous -> a wave's B-frag load
// is one fully-coalesced 1 KB burst at base + f*1024 + l*16.
// ---------------------------------------------------------------------------
// src fp32 row-major [N,K] (torch [out,in] layout)
__global__ void pack_direct_k(const float* __restrict__ src, ushort* __restrict__ dst,
                              int N, int K) {
    int total = (N >> 4) * (K >> 5) * 64;
    int idx = blockIdx.x * 256 + threadIdx.x;
    if (idx >= total) return;
    int l = idx & 63, f = idx >> 6;
    int kfrags = K >> 5;
    int nt = f / kfrags, kf = f - nt * kfrags;
    int n = nt * 16 + (l & 15);
    int k0 = kf * 32 + (l >> 4) * 8;
    const float* s = src + (size_t)n * K + k0;
    ushort8 u;
#pragma unroll
    for (int j = 0; j < 8; j++) u[j] = f2bf(s[j]);
    *(ushort8*)&dst[(size_t)f * 512 + l * 8] = u;
}
// src fp32 row-major [K,N] (jax [in,out] layout); logical B is its transpose
__global__ void pack_trans_k(const float* __restrict__ src, ushort* __restrict__ dst,
                             int N, int K) {
    int total = (N >> 4) * (K >> 5) * 64;
    int idx = blockIdx.x * 256 + threadIdx.x;
    if (idx >= total) return;
    int l = idx & 63, f = idx >> 6;
    int kfrags = K >> 5;
    int nt = f / kfrags, kf = f - nt * kfrags;
    int n = nt * 16 + (l & 15);
    int k0 = kf * 32 + (l >> 4) * 8;
    ushort8 u;
#pragma unroll
    for (int j = 0; j < 8; j++) u[j] = f2bf(src[(size_t)(k0 + j) * N + n]);
    *(ushort8*)&dst[(size_t)f * 512 + l * 8] = u;
}

// ---------------------------------------------------------------------------
// Fully fused scan: 32 WGs x 512 thr (8 waves). WG owns 16 batch rows.
// Per step t: stage H -> GEMM1 (relu) -> GEMM2 -> 4 ODE substeps -> GRU ->
// out projection. h fp32 master + bf16 mirror in LDS. All weights read from
// fragment-packed global buffers (coalesced 1 KB/load, L2/L3-resident).
// ---------------------------------------------------------------------------
__global__ __launch_bounds__(512) void scan_fused(
    const float*  __restrict__ H,     // [65536,128] fp32, row = b*128+t
    const ushort* __restrict__ W1P,   // packed N=512,K=128
    const float*  __restrict__ b1,    // [512]
    const ushort* __restrict__ W2P,   // packed N=256,K=512
    const float*  __restrict__ b2,    // [256]
    const ushort* __restrict__ OhrP, const ushort* __restrict__ OhzP,
    const ushort* __restrict__ OhhP,  // packed N=256,K=256
    const ushort* __restrict__ WihP,  // packed N=768,K=256
    const ushort* __restrict__ WhhP,  // packed N=768,K=256
    const float*  __restrict__ bih,   // [768]
    const float*  __restrict__ bhh,   // [768]
    const ushort* __restrict__ WrP,   // packed N=128,K=256
    const float*  __restrict__ br,    // [128]
    float* __restrict__ out)          // [65536,128] fp32, row = b*128+t
{
    const int m0 = blockIdx.x * 16;
    const int tid = threadIdx.x;
    const int w = tid >> 6, lane = tid & 63;
    const int q = lane >> 4, tc = lane & 15;
    const int lo8 = lane * 8;  // packed-fragment lane offset (ushorts)

    __shared__ __align__(16) ushort sx[16][136];    // H tile bf16 (K=128)
    __shared__ __align__(16) ushort sT[16][520];    // T1 bf16 (K=512)
    __shared__ __align__(16) ushort x_bf[16][264];  // x_t bf16 (K=256)
    __shared__ __align__(16) ushort h_bf[16][264];
    __shared__ __align__(16) ushort rh_bf[16][264];
    __shared__ __align__(16) float h_f[16][264];
    __shared__ float b1s[512], b2s[256], bihs[768], bhhs[768], brs[128];

    for (int i = tid; i < 16 * 264; i += 512) (&h_bf[0][0])[i] = 0;
    for (int i = tid; i < 16 * 264; i += 512) (&h_f[0][0])[i] = 0.f;
    if (tid < 512) b1s[tid] = b1[tid];
    if (tid < 256) b2s[tid] = b2[tid];
    for (int i = tid; i < 768; i += 512) { bihs[i] = bih[i]; bhhs[i] = bhh[i]; }
    if (tid < 128) brs[tid] = br[tid];
    __syncthreads();

    const int colbase = w * 32 + tc;  // + nt*16: 8 waves cover cols 0..255

#pragma unroll 1
    for (int t = 0; t < 128; t++) {
        // ---- 1. stage H rows for step t (fp32 -> bf16) ----
        if (tid < 256) {
            int r = tid >> 4, c = (tid & 15) * 8;
            const float* hp = &H[((size_t)(m0 + r) * 128 + t) * 128 + c];
            float4 v0 = *(const float4*)hp;
            float4 v1 = *(const float4*)(hp + 4);
            ushort8 u;
            u[0] = f2bf(v0.x); u[1] = f2bf(v0.y); u[2] = f2bf(v0.z); u[3] = f2bf(v0.w);
            u[4] = f2bf(v1.x); u[5] = f2bf(v1.y); u[6] = f2bf(v1.z); u[7] = f2bf(v1.w);
            *(ushort8*)&sx[r][c] = u;
        }
        __syncthreads();

        // ---- 2. GEMM1: T1 = relu(sx @ W1^T + b1), N=512 K=128 ----
        {
            bf16x8 a1[4];
#pragma unroll
            for (int kb = 0; kb < 4; kb++)
                a1[kb] = *(const bf16x8*)&sx[tc][kb * 32 + q * 8];
#pragma unroll
            for (int j = 0; j < 4; j++) {
                int n = w * 64 + j * 16 + tc;
                const ushort* bp = W1P + (size_t)(w * 4 + j) * 4 * 512 + lo8;
                f32x4 a = Z4;
#pragma unroll
                for (int kb = 0; kb < 4; kb++)
                    a = mfma16(a1[kb], *(const bf16x8*)&bp[kb * 512], a);
                float bv = b1s[n];
#pragma unroll
                for (int i = 0; i < 4; i++)
                    sT[q * 4 + i][n] = f2bf(fmaxf(a[i] + bv, 0.f));
            }
        }
        __syncthreads();

        // ---- 3. GEMM2: x_t = sT @ W2^T + b2, N=256 K=512 ----
        {
            bf16x8 a2[16];
#pragma unroll
            for (int kb = 0; kb < 16; kb++)
                a2[kb] = *(const bf16x8*)&sT[tc][kb * 32 + q * 8];
#pragma unroll
            for (int nt = 0; nt < 2; nt++) {
                int n = colbase + nt * 16;
                const ushort* bp = W2P + (size_t)(w * 2 + nt) * 16 * 512 + lo8;
                f32x4 a = Z4;
#pragma unroll
                for (int kb = 0; kb < 16; kb++)
                    a = mfma16(a2[kb], *(const bf16x8*)&bp[kb * 512], a);
                float bv = b2s[n];
#pragma unroll
                for (int i = 0; i < 4; i++)
                    x_bf[q * 4 + i][n] = f2bf(a[i] + bv);
            }
        }
        // x_bf first read 8+ syncs later (GRU); sT reads done before next
        // step's sync#2; no extra barrier needed here.

        // ---- 4. 4 Euler ODE substeps (K=256 matmuls vs Ohr/Ohz/Ohh) ----
#pragma unroll 1
        for (int s = 0; s < 4; s++) {
            bf16x8 af[8];
#pragma unroll
            for (int k = 0; k < 8; k++) af[k] = *(const bf16x8*)&h_bf[tc][k * 32 + q * 8];

            f32x4 ar[2], az[2];
#pragma unroll
            for (int nt = 0; nt < 2; nt++) {
                const ushort* pr = OhrP + (size_t)(w * 2 + nt) * 8 * 512 + lo8;
                const ushort* pz = OhzP + (size_t)(w * 2 + nt) * 8 * 512 + lo8;
                f32x4 r = Z4, z = Z4;
#pragma unroll
                for (int k = 0; k < 8; k++) {
                    r = mfma16(af[k], *(const bf16x8*)&pr[k * 512], r);
                    z = mfma16(af[k], *(const bf16x8*)&pz[k * 512], z);
                }
                ar[nt] = r; az[nt] = z;
            }

            float zs[2][4];
#pragma unroll
            for (int nt = 0; nt < 2; nt++) {
                int col = colbase + nt * 16;
#pragma unroll
                for (int i = 0; i < 4; i++) {
                    int row = q * 4 + i;
                    float rv = sigmoidf_(ar[nt][i]);
                    zs[nt][i] = sigmoidf_(az[nt][i]);
                    rh_bf[row][col] = f2bf(rv * h_f[row][col]);
                }
            }
            __syncthreads();  // rh complete; h_bf reads of phase 1 done

            bf16x8 au[8];
#pragma unroll
            for (int k = 0; k < 8; k++) au[k] = *(const bf16x8*)&rh_bf[tc][k * 32 + q * 8];
            f32x4 uu[2];
#pragma unroll
            for (int nt = 0; nt < 2; nt++) {
                const ushort* ph = OhhP + (size_t)(w * 2 + nt) * 8 * 512 + lo8;
                f32x4 u = Z4;
#pragma unroll
                for (int k = 0; k < 8; k++)
                    u = mfma16(au[k], *(const bf16x8*)&ph[k * 512], u);
                uu[nt] = u;
            }
#pragma unroll
            for (int nt = 0; nt < 2; nt++) {
                int col = colbase + nt * 16;
#pragma unroll
                for (int i = 0; i < 4; i++) {
                    int row = q * 4 + i;
                    float hv = h_f[row][col];
                    float uv = tanhf_(uu[nt][i]);
                    float hn = hv + 0.25f * (1.f - zs[nt][i]) * (uv - hv);
                    h_f[row][col] = hn;
                    h_bf[row][col] = f2bf(hn);
                }
            }
            __syncthreads();  // h updated for next phase
        }

        // ---- 5. GRU cell: K=512 split matmul (x part + h part) ----
        {
            bf16x8 ah[8], ax[8];
#pragma unroll
            for (int k = 0; k < 8; k++) {
                ah[k] = *(const bf16x8*)&h_bf[tc][k * 32 + q * 8];
                ax[k] = *(const bf16x8*)&x_bf[tc][k * 32 + q * 8];
            }
            f32x4 acc_r[2], acc_z[2], acc_xn[2], acc_hn[2];
#pragma unroll
            for (int nt = 0; nt < 2; nt++) {
                // gate g row-block: ntile = g*16 + w*2 + nt (N=768 packed)
                const ushort* pxr = WihP + (size_t)(0  * 16 + w * 2 + nt) * 8 * 512 + lo8;
                const ushort* pxz = WihP + (size_t)(1  * 16 + w * 2 + nt) * 8 * 512 + lo8;
                const ushort* pxn = WihP + (size_t)(2  * 16 + w * 2 + nt) * 8 * 512 + lo8;
                const ushort* phr = WhhP + (size_t)(0  * 16 + w * 2 + nt) * 8 * 512 + lo8;
                const ushort* phz = WhhP + (size_t)(1  * 16 + w * 2 + nt) * 8 * 512 + lo8;
                const ushort* phn = WhhP + (size_t)(2  * 16 + w * 2 + nt) * 8 * 512 + lo8;
                f32x4 r = Z4, z = Z4, xn = Z4, hn = Z4;
#pragma unroll
                for (int k = 0; k < 8; k++) {
                    r  = mfma16(ax[k], *(const bf16x8*)&pxr[k * 512], r);
                    z  = mfma16(ax[k], *(const bf16x8*)&pxz[k * 512], z);
                    xn = mfma16(ax[k], *(const bf16x8*)&pxn[k * 512], xn);
                }
#pragma unroll
                for (int k = 0; k < 8; k++) {
                    r  = mfma16(ah[k], *(const bf16x8*)&phr[k * 512], r);
                    z  = mfma16(ah[k], *(const bf16x8*)&phz[k * 512], z);
                    hn = mfma16(ah[k], *(const bf16x8*)&phn[k * 512], hn);
                }
                acc_r[nt] = r; acc_z[nt] = z; acc_xn[nt] = xn; acc_hn[nt] = hn;
            }
            __syncthreads();  // all h_bf/x_bf reads done before h update

#pragma unroll
            for (int nt = 0; nt < 2; nt++) {
                int col = colbase + nt * 16;
#pragma unroll
                for (int i = 0; i < 4; i++) {
                    int row = q * 4 + i;
                    float rg = sigmoidf_(acc_r[nt][i] + bihs[col] + bhhs[col]);
                    float zg = sigmoidf_(acc_z[nt][i] + bihs[256 + col] + bhhs[256 + col]);
                    float ng = tanhf_(acc_xn[nt][i] + bihs[512 + col] +
                                      rg * (acc_hn[nt][i] + bhhs[512 + col]));
                    float hv = h_f[row][col];
                    float hn = (1.f - zg) * ng + zg * hv;
                    h_f[row][col] = hn;
                    h_bf[row][col] = f2bf(hn);
                }
            }
        }
        __syncthreads();  // h_new visible for projection

        // ---- 6. output projection: out_t = h_new @ Wr + br (fp32 out) ----
        {
            bf16x8 ap[8];
#pragma unroll
            for (int k = 0; k < 8; k++) ap[k] = *(const bf16x8*)&h_bf[tc][k * 32 + q * 8];
            int n = w * 16 + tc;  // 8 waves x 16 = 128 out cols
            const ushort* pw = WrP + (size_t)w * 8 * 512 + lo8;
            f32x4 a = Z4;
#pragma unroll
            for (int k = 0; k < 8; k++)
                a = mfma16(ap[k], *(const bf16x8*)&pw[k * 512], a);
            float bv = brs[n];
#pragma unroll
            for (int i = 0; i < 4; i++)
                out[(size_t)((m0 + q * 4 + i) * 128 + t) * 128 + n] = a[i] + bv;
        }
        // safe: any thread entering step t+1 blocks at sync#1 before touching
        // sT/h_bf; sx/x_bf writes there conflict with nothing read here.
    }
}

// ---------------------------------------------------------------------------
// Launch.  Workspace: 1.64 MB of fragment-packed bf16 weights.
//   [0,       131072)   W1P  (N=512,K=128)
//   [131072,  393216)   W2P  (N=256,K=512)
//   [393216,  458752)   WrP  (N=128,K=256)
//   [458752,  589824)   OhrP (N=256,K=256)
//   [589824,  720896)   OhzP
//   [720896,  851968)   OhhP
//   [851968, 1245184)   WihP (N=768,K=256)
//   [1245184,1638400)   WhhP (N=768,K=256)
// ---------------------------------------------------------------------------
extern "C" void kernel_launch(void* const* d_in, const int* in_sizes, int n_in,
                              void* d_out, int out_size, void* d_ws, size_t ws_size,
                              hipStream_t stream) {
    const float* H   = (const float*)d_in[0];   // [512,128,128]
    // d_in[1] = times (unused; unit spacing -> 4 fixed Euler substeps)
    const float* W1  = (const float*)d_in[2];   // [128,512] (in,out)
    const float* b1  = (const float*)d_in[3];
    const float* W2  = (const float*)d_in[4];   // [512,256]
    const float* b2  = (const float*)d_in[5];
    const float* Ohr = (const float*)d_in[6];   // [256,256] (out,in)
    const float* Ohz = (const float*)d_in[7];
    const float* Ohh = (const float*)d_in[8];
    const float* Wih = (const float*)d_in[9];   // [768,256] (out,in)
    const float* Whh = (const float*)d_in[10];  // [768,256]
    const float* bih = (const float*)d_in[11];
    const float* bhh = (const float*)d_in[12];
    const float* Wr  = (const float*)d_in[13];  // [256,128] (in,out)
    const float* br  = (const float*)d_in[14];
    float* out = (float*)d_out;                 // [512,128,128]
    char* ws = (char*)d_ws;

    ushort* W1P  = (ushort*)(ws);
    ushort* W2P  = (ushort*)(ws + 131072);
    ushort* WrP  = (ushort*)(ws + 393216);
    ushort* OhrP = (ushort*)(ws + 458752);
    ushort* OhzP = (ushort*)(ws + 589824);
    ushort* OhhP = (ushort*)(ws + 720896);
    ushort* WihP = (ushort*)(ws + 851968);
    ushort* WhhP = (ushort*)(ws + 1245184);

    // pack: grid = total/256, total = (N/16)*(K/32)*64
    pack_trans_k<<<dim3(32),  256, 0, stream>>>(W1,  W1P, 512, 128);
    pack_trans_k<<<dim3(64),  256, 0, stream>>>(W2,  W2P, 256, 512);
    pack_trans_k<<<dim3(16),  256, 0, stream>>>(Wr,  WrP, 128, 256);
    pack_direct_k<<<dim3(32), 256, 0, stream>>>(Ohr, OhrP, 256, 256);
    pack_direct_k<<<dim3(32), 256, 0, stream>>>(Ohz, OhzP, 256, 256);
    pack_direct_k<<<dim3(32), 256, 0, stream>>>(Ohh, OhhP, 256, 256);
    pack_direct_k<<<dim3(96), 256, 0, stream>>>(Wih, WihP, 768, 256);
    pack_direct_k<<<dim3(96), 256, 0, stream>>>(Whh, WhhP, 768, 256);

    scan_fused<<<dim3(32), 512, 0, stream>>>(H, W1P, b1, W2P, b2,
                                             OhrP, OhzP, OhhP, WihP, WhhP,
                                             bih, bhh, WrP, br, out);
}

// Round 6
// 7672.488 us; speedup vs baseline: 1.0433x; 1.0433x over previous
//
#include <hip/hip_runtime.h>

typedef unsigned short ushort;
typedef unsigned int uint;
typedef __bf16 bf16x8 __attribute__((ext_vector_type(8)));
typedef ushort ushort8 __attribute__((ext_vector_type(8)));
typedef float f32x4 __attribute__((ext_vector_type(4)));

#define Z4 f32x4{0.f, 0.f, 0.f, 0.f}

__device__ __forceinline__ f32x4 mfma16(bf16x8 a, bf16x8 b, f32x4 c) {
    return __builtin_amdgcn_mfma_f32_16x16x32_bf16(a, b, c, 0, 0, 0);
}

__device__ __forceinline__ ushort f2bf(float f) {  // RNE
    union { float f; uint u; } v; v.f = f;
    uint u = v.u;
    uint r = (u + 0x7fffu + ((u >> 16) & 1u)) >> 16;
    return (ushort)r;
}
__device__ __forceinline__ float sigmoidf_(float x) { return 1.f / (1.f + __expf(-x)); }
__device__ __forceinline__ float tanhf_(float x) {
    float e = __expf(2.f * x);
    return 1.f - 2.f / (e + 1.f);
}

// ---------------------------------------------------------------------------
// Weight pre-pack into MFMA-B fragment-major layout (see round 5).
// fragment f = ntile*(K/32) + kf; lane l holds src(nt*16+(l&15), kf*32+(l>>4)*8+j)
// ---------------------------------------------------------------------------
__global__ void pack_direct_k(const float* __restrict__ src, ushort* __restrict__ dst,
                              int N, int K) {
    int total = (N >> 4) * (K >> 5) * 64;
    int idx = blockIdx.x * 256 + threadIdx.x;
    if (idx >= total) return;
    int l = idx & 63, f = idx >> 6;
    int kfrags = K >> 5;
    int nt = f / kfrags, kf = f - nt * kfrags;
    int n = nt * 16 + (l & 15);
    int k0 = kf * 32 + (l >> 4) * 8;
    const float* s = src + (size_t)n * K + k0;
    ushort8 u;
#pragma unroll
    for (int j = 0; j < 8; j++) u[j] = f2bf(s[j]);
    *(ushort8*)&dst[(size_t)f * 512 + l * 8] = u;
}
__global__ void pack_trans_k(const float* __restrict__ src, ushort* __restrict__ dst,
                             int N, int K) {
    int total = (N >> 4) * (K >> 5) * 64;
    int idx = blockIdx.x * 256 + threadIdx.x;
    if (idx >= total) return;
    int l = idx & 63, f = idx >> 6;
    int kfrags = K >> 5;
    int nt = f / kfrags, kf = f - nt * kfrags;
    int n = nt * 16 + (l & 15);
    int k0 = kf * 32 + (l >> 4) * 8;
    ushort8 u;
#pragma unroll
    for (int j = 0; j < 8; j++) u[j] = f2bf(src[(size_t)(k0 + j) * N + n]);
    *(ushort8*)&dst[(size_t)f * 512 + l * 8] = u;
}

// ---------------------------------------------------------------------------
// Fused scan v2: batched/pipelined B-fragment loads, 256-VGPR budget.
// 32 WGs x 512 thr; WG owns 16 batch rows; h fp32 + bf16 mirror in LDS.
// Ohr/Ohz register-resident per step (4x reuse); all phases load B-frags in
// batches before their MFMA chains; cross-phase prefetch where pressure allows.
// ---------------------------------------------------------------------------
__global__ __launch_bounds__(512, 2) void scan_fused(
    const float*  __restrict__ H,     // [65536,128] fp32, row = b*128+t
    const ushort* __restrict__ W1P,   // packed N=512,K=128
    const float*  __restrict__ b1,
    const ushort* __restrict__ W2P,   // packed N=256,K=512
    const float*  __restrict__ b2,
    const ushort* __restrict__ OhrP, const ushort* __restrict__ OhzP,
    const ushort* __restrict__ OhhP,  // packed N=256,K=256
    const ushort* __restrict__ WihP,  // packed N=768,K=256
    const ushort* __restrict__ WhhP,  // packed N=768,K=256
    const float*  __restrict__ bih,
    const float*  __restrict__ bhh,
    const ushort* __restrict__ WrP,   // packed N=128,K=256
    const float*  __restrict__ br,
    float* __restrict__ out)          // [65536,128] fp32, row = b*128+t
{
    const int m0 = blockIdx.x * 16;
    const int tid = threadIdx.x;
    const int w = tid >> 6, lane = tid & 63;
    const int q = lane >> 4, tc = lane & 15;
    const int lo8 = lane * 8;

    __shared__ __align__(16) ushort sx[16][136];
    __shared__ __align__(16) ushort sT[16][520];
    __shared__ __align__(16) ushort x_bf[16][264];
    __shared__ __align__(16) ushort h_bf[16][264];
    __shared__ __align__(16) ushort rh_bf[16][264];
    __shared__ __align__(16) float h_f[16][264];
    __shared__ float b1s[512], b2s[256], bihs[768], bhhs[768], brs[128];

    for (int i = tid; i < 16 * 264; i += 512) (&h_bf[0][0])[i] = 0;
    for (int i = tid; i < 16 * 264; i += 512) (&h_f[0][0])[i] = 0.f;
    b1s[tid] = b1[tid];
    if (tid < 256) b2s[tid] = b2[tid];
    for (int i = tid; i < 768; i += 512) { bihs[i] = bih[i]; bhhs[i] = bhh[i]; }
    if (tid < 128) brs[tid] = br[tid];
    __syncthreads();

    const int colbase = w * 32 + tc;

    // wave-static fragment base pointers
    const ushort* w1base = W1P + (size_t)(w * 4) * 4 * 512 + lo8;   // +j*2048+kb*512
    const ushort* w2base = W2P + (size_t)(w * 2) * 16 * 512 + lo8;  // +nt*8192+kb*512
    const ushort* orbase = OhrP + (size_t)(w * 2) * 8 * 512 + lo8;  // +nt*4096+k*512
    const ushort* ozbase = OhzP + (size_t)(w * 2) * 8 * 512 + lo8;
    const ushort* ohbase = OhhP + (size_t)(w * 2) * 8 * 512 + lo8;
    const ushort* wpbase = WrP + (size_t)w * 8 * 512 + lo8;         // +k*512

#pragma unroll 1
    for (int t = 0; t < 128; t++) {
        // ---- issue W1 frags early, then stage H (fp32 -> bf16) ----
        bf16x8 w1f[16];
#pragma unroll
        for (int j = 0; j < 4; j++)
#pragma unroll
            for (int kb = 0; kb < 4; kb++)
                w1f[j * 4 + kb] = *(const bf16x8*)(w1base + j * 2048 + kb * 512);

        if (tid < 256) {
            int r = tid >> 4, c = (tid & 15) * 8;
            const float* hp = &H[((size_t)(m0 + r) * 128 + t) * 128 + c];
            float4 v0 = *(const float4*)hp;
            float4 v1 = *(const float4*)(hp + 4);
            ushort8 u;
            u[0] = f2bf(v0.x); u[1] = f2bf(v0.y); u[2] = f2bf(v0.z); u[3] = f2bf(v0.w);
            u[4] = f2bf(v1.x); u[5] = f2bf(v1.y); u[6] = f2bf(v1.z); u[7] = f2bf(v1.w);
            *(ushort8*)&sx[r][c] = u;
        }
        __syncthreads();

        // ---- GEMM1: T1 = relu(sx @ W1^T + b1) ----
        bf16x8 w2f0[16];
        {
            bf16x8 a1[4];
#pragma unroll
            for (int kb = 0; kb < 4; kb++)
                a1[kb] = *(const bf16x8*)&sx[tc][kb * 32 + q * 8];
            f32x4 t1a[4];
#pragma unroll
            for (int j = 0; j < 4; j++) {
                f32x4 a = Z4;
#pragma unroll
                for (int kb = 0; kb < 4; kb++)
                    a = mfma16(a1[kb], w1f[j * 4 + kb], a);
                t1a[j] = a;
            }
            // prefetch GEMM2 nt=0 frags while epilogue runs
#pragma unroll
            for (int kb = 0; kb < 16; kb++)
                w2f0[kb] = *(const bf16x8*)(w2base + kb * 512);
#pragma unroll
            for (int j = 0; j < 4; j++) {
                int n = w * 64 + j * 16 + tc;
                float bv = b1s[n];
#pragma unroll
                for (int i = 0; i < 4; i++)
                    sT[q * 4 + i][n] = f2bf(fmaxf(t1a[j][i] + bv, 0.f));
            }
        }
        __syncthreads();

        // ---- GEMM2: x_t = sT @ W2^T + b2 (nt=1 frags load under nt=0 MFMA) ----
        {
            bf16x8 a2[16];
#pragma unroll
            for (int kb = 0; kb < 16; kb++)
                a2[kb] = *(const bf16x8*)&sT[tc][kb * 32 + q * 8];
            bf16x8 w2f1[16];
#pragma unroll
            for (int kb = 0; kb < 16; kb++)
                w2f1[kb] = *(const bf16x8*)(w2base + 8192 + kb * 512);
            f32x4 x0 = Z4, x1 = Z4;
#pragma unroll
            for (int kb = 0; kb < 16; kb++) x0 = mfma16(a2[kb], w2f0[kb], x0);
#pragma unroll
            for (int kb = 0; kb < 16; kb++) x1 = mfma16(a2[kb], w2f1[kb], x1);
            int n0 = colbase, n1 = colbase + 16;
            float bv0 = b2s[n0], bv1 = b2s[n1];
#pragma unroll
            for (int i = 0; i < 4; i++) {
                x_bf[q * 4 + i][n0] = f2bf(x0[i] + bv0);
                x_bf[q * 4 + i][n1] = f2bf(x1[i] + bv1);
            }
        }

        // ---- ODE r/z weights: load once per step, reuse 4x from registers ----
        bf16x8 wOr[16], wOz[16];
#pragma unroll
        for (int nt = 0; nt < 2; nt++)
#pragma unroll
            for (int k = 0; k < 8; k++) {
                wOr[nt * 8 + k] = *(const bf16x8*)(orbase + nt * 4096 + k * 512);
                wOz[nt * 8 + k] = *(const bf16x8*)(ozbase + nt * 4096 + k * 512);
            }

        // ---- 4 Euler ODE substeps ----
#pragma unroll 1
        for (int s = 0; s < 4; s++) {
            bf16x8 af[8];
#pragma unroll
            for (int k = 0; k < 8; k++) af[k] = *(const bf16x8*)&h_bf[tc][k * 32 + q * 8];

            f32x4 ar[2], az[2];
#pragma unroll
            for (int nt = 0; nt < 2; nt++) {
                f32x4 r = Z4, z = Z4;
#pragma unroll
                for (int k = 0; k < 8; k++) {
                    r = mfma16(af[k], wOr[nt * 8 + k], r);
                    z = mfma16(af[k], wOz[nt * 8 + k], z);
                }
                ar[nt] = r; az[nt] = z;
            }

            float zs[2][4];
#pragma unroll
            for (int nt = 0; nt < 2; nt++) {
                int col = colbase + nt * 16;
#pragma unroll
                for (int i = 0; i < 4; i++) {
                    int row = q * 4 + i;
                    float rv = sigmoidf_(ar[nt][i]);
                    zs[nt][i] = sigmoidf_(az[nt][i]);
                    rh_bf[row][col] = f2bf(rv * h_f[row][col]);
                }
            }
            __syncthreads();

            bf16x8 wh[16];
#pragma unroll
            for (int nt = 0; nt < 2; nt++)
#pragma unroll
                for (int k = 0; k < 8; k++)
                    wh[nt * 8 + k] = *(const bf16x8*)(ohbase + nt * 4096 + k * 512);
            bf16x8 au[8];
#pragma unroll
            for (int k = 0; k < 8; k++) au[k] = *(const bf16x8*)&rh_bf[tc][k * 32 + q * 8];
            f32x4 uu[2];
#pragma unroll
            for (int nt = 0; nt < 2; nt++) {
                f32x4 u = Z4;
#pragma unroll
                for (int k = 0; k < 8; k++)
                    u = mfma16(au[k], wh[nt * 8 + k], u);
                uu[nt] = u;
            }
#pragma unroll
            for (int nt = 0; nt < 2; nt++) {
                int col = colbase + nt * 16;
#pragma unroll
                for (int i = 0; i < 4; i++) {
                    int row = q * 4 + i;
                    float hv = h_f[row][col];
                    float uv = tanhf_(uu[nt][i]);
                    float hn = hv + 0.25f * (1.f - zs[nt][i]) * (uv - hv);
                    h_f[row][col] = hn;
                    h_bf[row][col] = f2bf(hn);
                }
            }
            __syncthreads();
        }

        // ---- GRU cell: 6 double-buffered batches of 16 B-frags ----
        f32x4 acc_r[2], acc_z[2], acc_xn[2], acc_hn[2];
        {
            bf16x8 ah[8], ax[8];
#pragma unroll
            for (int k = 0; k < 8; k++) {
                ah[k] = *(const bf16x8*)&h_bf[tc][k * 32 + q * 8];
                ax[k] = *(const bf16x8*)&x_bf[tc][k * 32 + q * 8];
            }
#pragma unroll
            for (int nt = 0; nt < 2; nt++) {
                acc_r[nt] = Z4; acc_z[nt] = Z4; acc_xn[nt] = Z4; acc_hn[nt] = Z4;
            }
            bf16x8 gb[2][16];
            // preload batch 0: (nt=0, gate r)
#pragma unroll
            for (int k = 0; k < 8; k++) {
                size_t off = (size_t)(0 * 16 + w * 2 + 0) * 8 * 512 + (size_t)k * 512 + lo8;
                gb[0][k] = *(const bf16x8*)(WihP + off);
                gb[0][8 + k] = *(const bf16x8*)(WhhP + off);
            }
#pragma unroll
            for (int b = 0; b < 6; b++) {
                const int cur = b & 1;
                if (b < 5) {
                    const int nb = b + 1;
                    const int nnt = nb / 3, ng = nb - nnt * 3;
#pragma unroll
                    for (int k = 0; k < 8; k++) {
                        size_t off = (size_t)(ng * 16 + w * 2 + nnt) * 8 * 512 +
                                     (size_t)k * 512 + lo8;
                        gb[1 - cur][k] = *(const bf16x8*)(WihP + off);
                        gb[1 - cur][8 + k] = *(const bf16x8*)(WhhP + off);
                    }
                }
                const int nt = b / 3, g = b - nt * 3;
                if (g == 0) {
#pragma unroll
                    for (int k = 0; k < 8; k++) acc_r[nt] = mfma16(ax[k], gb[cur][k], acc_r[nt]);
#pragma unroll
                    for (int k = 0; k < 8; k++) acc_r[nt] = mfma16(ah[k], gb[cur][8 + k], acc_r[nt]);
                } else if (g == 1) {
#pragma unroll
                    for (int k = 0; k < 8; k++) acc_z[nt] = mfma16(ax[k], gb[cur][k], acc_z[nt]);
#pragma unroll
                    for (int k = 0; k < 8; k++) acc_z[nt] = mfma16(ah[k], gb[cur][8 + k], acc_z[nt]);
                } else {
#pragma unroll
                    for (int k = 0; k < 8; k++) acc_xn[nt] = mfma16(ax[k], gb[cur][k], acc_xn[nt]);
#pragma unroll
                    for (int k = 0; k < 8; k++) acc_hn[nt] = mfma16(ah[k], gb[cur][8 + k], acc_hn[nt]);
                }
            }
        }
        // prefetch projection frags before the epilogue barrier
        bf16x8 wp[8];
#pragma unroll
        for (int k = 0; k < 8; k++) wp[k] = *(const bf16x8*)(wpbase + k * 512);
        __syncthreads();  // all h_bf/x_bf reads done before h update

#pragma unroll
        for (int nt = 0; nt < 2; nt++) {
            int col = colbase + nt * 16;
#pragma unroll
            for (int i = 0; i < 4; i++) {
                int row = q * 4 + i;
                float rg = sigmoidf_(acc_r[nt][i] + bihs[col] + bhhs[col]);
                float zg = sigmoidf_(acc_z[nt][i] + bihs[256 + col] + bhhs[256 + col]);
                float ng = tanhf_(acc_xn[nt][i] + bihs[512 + col] +
                                  rg * (acc_hn[nt][i] + bhhs[512 + col]));
                float hv = h_f[row][col];
                float hn = (1.f - zg) * ng + zg * hv;
                h_f[row][col] = hn;
                h_bf[row][col] = f2bf(hn);
            }
        }
        __syncthreads();  // h_new visible for projection

        // ---- output projection ----
        {
            bf16x8 ap[8];
#pragma unroll
            for (int k = 0; k < 8; k++) ap[k] = *(const bf16x8*)&h_bf[tc][k * 32 + q * 8];
            int n = w * 16 + tc;
            f32x4 a = Z4;
#pragma unroll
            for (int k = 0; k < 8; k++)
                a = mfma16(ap[k], wp[k], a);
            float bv = brs[n];
#pragma unroll
            for (int i = 0; i < 4; i++)
                out[(size_t)((m0 + q * 4 + i) * 128 + t) * 128 + n] = a[i] + bv;
        }
    }
}

// ---------------------------------------------------------------------------
// Launch.  Workspace: 1.64 MB fragment-packed bf16 weights.
// ---------------------------------------------------------------------------
extern "C" void kernel_launch(void* const* d_in, const int* in_sizes, int n_in,
                              void* d_out, int out_size, void* d_ws, size_t ws_size,
                              hipStream_t stream) {
    const float* H   = (const float*)d_in[0];
    const float* W1  = (const float*)d_in[2];
    const float* b1  = (const float*)d_in[3];
    const float* W2  = (const float*)d_in[4];
    const float* b2  = (const float*)d_in[5];
    const float* Ohr = (const float*)d_in[6];
    const float* Ohz = (const float*)d_in[7];
    const float* Ohh = (const float*)d_in[8];
    const float* Wih = (const float*)d_in[9];
    const float* Whh = (const float*)d_in[10];
    const float* bih = (const float*)d_in[11];
    const float* bhh = (const float*)d_in[12];
    const float* Wr  = (const float*)d_in[13];
    const float* br  = (const float*)d_in[14];
    float* out = (float*)d_out;
    char* ws = (char*)d_ws;

    ushort* W1P  = (ushort*)(ws);
    ushort* W2P  = (ushort*)(ws + 131072);
    ushort* WrP  = (ushort*)(ws + 393216);
    ushort* OhrP = (ushort*)(ws + 458752);
    ushort* OhzP = (ushort*)(ws + 589824);
    ushort* OhhP = (ushort*)(ws + 720896);
    ushort* WihP = (ushort*)(ws + 851968);
    ushort* WhhP = (ushort*)(ws + 1245184);

    pack_trans_k<<<dim3(32),  256, 0, stream>>>(W1,  W1P, 512, 128);
    pack_trans_k<<<dim3(64),  256, 0, stream>>>(W2,  W2P, 256, 512);
    pack_trans_k<<<dim3(16),  256, 0, stream>>>(Wr,  WrP, 128, 256);
    pack_direct_k<<<dim3(32), 256, 0, stream>>>(Ohr, OhrP, 256, 256);
    pack_direct_k<<<dim3(32), 256, 0, stream>>>(Ohz, OhzP, 256, 256);
    pack_direct_k<<<dim3(32), 256, 0, stream>>>(Ohh, OhhP, 256, 256);
    pack_direct_k<<<dim3(96), 256, 0, stream>>>(Wih, WihP, 768, 256);
    pack_direct_k<<<dim3(96), 256, 0, stream>>>(Whh, WhhP, 768, 256);

    scan_fused<<<dim3(32), 512, 0, stream>>>(H, W1P, b1, W2P, b2,
                                             OhrP, OhzP, OhhP, WihP, WhhP,
                                             bih, bhh, WrP, br, out);
}

// Round 7
// 4860.051 us; speedup vs baseline: 1.6470x; 1.5787x over previous
//
#include <hip/hip_runtime.h>

typedef unsigned short ushort;
typedef unsigned int uint;
typedef __bf16 bf16x8 __attribute__((ext_vector_type(8)));
typedef ushort ushort8 __attribute__((ext_vector_type(8)));
typedef float f32x4 __attribute__((ext_vector_type(4)));

#define Z4 f32x4{0.f, 0.f, 0.f, 0.f}

__device__ __forceinline__ f32x4 mfma16(bf16x8 a, bf16x8 b, f32x4 c) {
    return __builtin_amdgcn_mfma_f32_16x16x32_bf16(a, b, c, 0, 0, 0);
}

__device__ __forceinline__ ushort f2bf(float f) {  // RNE
    union { float f; uint u; } v; v.f = f;
    uint u = v.u;
    uint r = (u + 0x7fffu + ((u >> 16) & 1u)) >> 16;
    return (ushort)r;
}
__device__ __forceinline__ float sigmoidf_(float x) { return 1.f / (1.f + __expf(-x)); }
__device__ __forceinline__ float tanhf_(float x) {
    float e = __expf(2.f * x);
    return 1.f - 2.f / (e + 1.f);
}

typedef __attribute__((address_space(1))) uint guint;
typedef __attribute__((address_space(3))) uint luint;

// one packed fragment: 64 lanes x 16B, dest = wave-uniform LDS base + lane*16
__device__ __forceinline__ void dma16(const ushort* g, ushort* l) {
    __builtin_amdgcn_global_load_lds((const guint*)g, (luint*)l, 16, 0, 0);
}

template <int N> __device__ __forceinline__ void ring_wait() {
    asm volatile("s_waitcnt vmcnt(%0)" ::"n"(N) : "memory");
}

// ---------------------------------------------------------------------------
// Weight pre-pack into MFMA-B fragment-major layout (unchanged from r5).
// fragment F = ntile*(K/32)+kf; 1 KB contiguous per fragment.
// ---------------------------------------------------------------------------
__global__ void pack_direct_k(const float* __restrict__ src, ushort* __restrict__ dst,
                              int N, int K) {
    int total = (N >> 4) * (K >> 5) * 64;
    int idx = blockIdx.x * 256 + threadIdx.x;
    if (idx >= total) return;
    int l = idx & 63, f = idx >> 6;
    int kfrags = K >> 5;
    int nt = f / kfrags, kf = f - nt * kfrags;
    int n = nt * 16 + (l & 15);
    int k0 = kf * 32 + (l >> 4) * 8;
    const float* s = src + (size_t)n * K + k0;
    ushort8 u;
#pragma unroll
    for (int j = 0; j < 8; j++) u[j] = f2bf(s[j]);
    *(ushort8*)&dst[(size_t)f * 512 + l * 8] = u;
}
__global__ void pack_trans_k(const float* __restrict__ src, ushort* __restrict__ dst,
                             int N, int K) {
    int total = (N >> 4) * (K >> 5) * 64;
    int idx = blockIdx.x * 256 + threadIdx.x;
    if (idx >= total) return;
    int l = idx & 63, f = idx >> 6;
    int kfrags = K >> 5;
    int nt = f / kfrags, kf = f - nt * kfrags;
    int n = nt * 16 + (l & 15);
    int k0 = kf * 32 + (l >> 4) * 8;
    ushort8 u;
#pragma unroll
    for (int j = 0; j < 8; j++) u[j] = f2bf(src[(size_t)(k0 + j) * N + n]);
    *(ushort8*)&dst[(size_t)f * 512 + l * 8] = u;
}

// ---------------------------------------------------------------------------
// Fused scan v3: all streamed weights go through an async global->LDS DMA
// ring (per-wave private, 3 slots x 4 frags x 1KB), vmcnt-pipelined, so
// in-flight depth is independent of the register allocator. Or/Oz persistent
// in VGPRs (reused 4x/step); h fp32 master in registers; biases in registers.
// Per-wave stream/step: W1 16 + W2 32 + Ohh 4x16 + GRU 96 + Wr 8 = 216 frags
// = 54 four-frag chunks (all phase boundaries divide by 4).
// ---------------------------------------------------------------------------
__global__ __launch_bounds__(512, 2) void scan_fused(
    const float*  __restrict__ H,     // [65536,128] fp32, row = b*128+t
    const ushort* __restrict__ W1P,   // packed N=512,K=128
    const float*  __restrict__ b1,
    const ushort* __restrict__ W2P,   // packed N=256,K=512
    const float*  __restrict__ b2,
    const ushort* __restrict__ OhrP, const ushort* __restrict__ OhzP,
    const ushort* __restrict__ OhhP,  // packed N=256,K=256
    const ushort* __restrict__ WihP,  // packed N=768,K=256
    const ushort* __restrict__ WhhP,  // packed N=768,K=256
    const float*  __restrict__ bih,
    const float*  __restrict__ bhh,
    const ushort* __restrict__ WrP,   // packed N=128,K=256
    const float*  __restrict__ br,
    float* __restrict__ out)          // [65536,128] fp32, row = b*128+t
{
    const int m0 = blockIdx.x * 16;
    const int tid = threadIdx.x;
    const int w = tid >> 6, lane = tid & 63;
    const int q = lane >> 4, tc = lane & 15;
    const int lo8 = lane * 8;

    __shared__ __align__(16) ushort ring[8][3][4][512];  // 96 KB
    __shared__ __align__(16) ushort sx[16][136];         // H tile bf16
    __shared__ __align__(16) ushort sT[16][520];         // T1 bf16 (rh aliased)
    __shared__ __align__(16) ushort x_bf[16][264];       // x_t bf16
    __shared__ __align__(16) ushort h_bf[16][264];       // h bf16 mirror
    ushort (*rh_bf)[520] = sT;  // r*h tile; lifetime disjoint from sT via barriers

    for (int i = tid; i < 16 * 264; i += 512) (&h_bf[0][0])[i] = 0;

    const int colbase = w * 32 + tc;
    const int cA = colbase, cB = colbase + 16;

    // ---- per-thread bias registers ----
    float b1v[4];
#pragma unroll
    for (int j = 0; j < 4; j++) b1v[j] = b1[w * 64 + j * 16 + tc];
    float b2v[2] = { b2[cA], b2[cB] };
    float rbv[2] = { bih[cA] + bhh[cA], bih[cB] + bhh[cB] };
    float zbv[2] = { bih[256 + cA] + bhh[256 + cA], bih[256 + cB] + bhh[256 + cB] };
    float xnbv[2] = { bih[512 + cA], bih[512 + cB] };
    float hnbv[2] = { bhh[512 + cA], bhh[512 + cB] };
    float brv = br[w * 16 + tc];

    // ---- persistent ODE r/z weight fragments (2 ntiles x 8 kf each) ----
    bf16x8 wOr[16], wOz[16];
#pragma unroll
    for (int nt = 0; nt < 2; nt++)
#pragma unroll
        for (int k = 0; k < 8; k++) {
            wOr[nt * 8 + k] = *(const bf16x8*)(OhrP + (size_t)(((w * 2 + nt) * 8 + k) * 512) + lo8);
            wOz[nt * 8 + k] = *(const bf16x8*)(OhzP + (size_t)(((w * 2 + nt) * 8 + k) * 512) + lo8);
        }

    float hreg[2][4] = {{0.f, 0.f, 0.f, 0.f}, {0.f, 0.f, 0.f, 0.f}};

    __syncthreads();

#pragma unroll 1
    for (int t = 0; t < 128; t++) {
        int ic = 0, islot = 0, slot = 0;

        auto pump = [&]() {
            if (ic >= 54) return;
            // ensure all pending LDS reads of the slot being overwritten executed
            asm volatile("s_waitcnt lgkmcnt(0)" ::: "memory");
            const ushort* g;
            int f0 = ic * 4;
            if (f0 < 16)       g = W1P + (size_t)(w * 16 + f0) * 512;
            else if (f0 < 48)  g = W2P + (size_t)(w * 32 + (f0 - 16)) * 512;
            else if (f0 < 112) g = OhhP + (size_t)(w * 16 + ((f0 - 48) & 15)) * 512;
            else if (f0 < 208) {
                int f = f0 - 112, b = f >> 3, k = f & 7;
                int bb = (b >= 6) ? b - 6 : b;
                int nt = bb / 3, gg = bb - nt * 3;
                g = ((b < 6) ? WihP : WhhP) + (size_t)(((gg * 16 + w * 2 + nt) * 8 + k) * 512);
            } else             g = WrP + (size_t)(w * 8 + (f0 - 208)) * 512;
            g += lo8;
            ushort* sb = &ring[w][islot][0][0];
            dma16(g,        sb);
            dma16(g + 512,  sb + 512);
            dma16(g + 1024, sb + 1024);
            dma16(g + 1536, sb + 1536);
            ic++; islot = (islot == 2) ? 0 : islot + 1;
        };
        auto rd4 = [&](bf16x8* v) {
            ring_wait<8>();  // oldest chunk (4 DMAs) complete; 2 chunks stay in flight
            const ushort* sb = &ring[w][slot][0][0] + lo8;
            v[0] = *(const bf16x8*)(sb);
            v[1] = *(const bf16x8*)(sb + 512);
            v[2] = *(const bf16x8*)(sb + 1024);
            v[3] = *(const bf16x8*)(sb + 1536);
            slot = (slot == 2) ? 0 : slot + 1;
        };

        pump(); pump(); pump();  // prime 3 chunks (12 DMAs in flight)

        // ---- stage H (fp32 -> bf16), one float4 per thread ----
        {
            int hr = tid >> 5, hc = (tid & 31) * 4;
            const float* hp = H + ((size_t)(m0 + hr) * 128 + t) * 128 + hc;
            float4 v = *(const float4*)hp;
            union { ushort u[4]; uint2 p; } pk;
            pk.u[0] = f2bf(v.x); pk.u[1] = f2bf(v.y);
            pk.u[2] = f2bf(v.z); pk.u[3] = f2bf(v.w);
            *(uint2*)&sx[hr][hc] = pk.p;
        }
        __syncthreads();  // B1: sx ready

        // ---- GEMM1: T1 = relu(sx @ W1^T + b1) : 4 chunks ----
        {
            bf16x8 a1[4];
#pragma unroll
            for (int kb = 0; kb < 4; kb++)
                a1[kb] = *(const bf16x8*)&sx[tc][kb * 32 + q * 8];
            f32x4 t1a[4];
#pragma unroll
            for (int j = 0; j < 4; j++) {
                bf16x8 v[4]; rd4(v);
                f32x4 a = Z4;
#pragma unroll
                for (int kb = 0; kb < 4; kb++) a = mfma16(a1[kb], v[kb], a);
                t1a[j] = a;
                pump();
            }
#pragma unroll
            for (int j = 0; j < 4; j++) {
                int n = w * 64 + j * 16 + tc;
#pragma unroll
                for (int i = 0; i < 4; i++)
                    sT[q * 4 + i][n] = f2bf(fmaxf(t1a[j][i] + b1v[j], 0.f));
            }
        }
        __syncthreads();  // B2: sT ready

        // ---- GEMM2: x_t = sT @ W2^T + b2 : 8 chunks ----
        {
            f32x4 xa[2] = { Z4, Z4 };
#pragma unroll
            for (int nt = 0; nt < 2; nt++)
#pragma unroll
                for (int cb = 0; cb < 4; cb++) {
                    bf16x8 aw[4], v[4];
#pragma unroll
                    for (int i = 0; i < 4; i++)
                        aw[i] = *(const bf16x8*)&sT[tc][(cb * 4 + i) * 32 + q * 8];
                    rd4(v);
#pragma unroll
                    for (int i = 0; i < 4; i++) xa[nt] = mfma16(aw[i], v[i], xa[nt]);
                    pump();
                }
#pragma unroll
            for (int i = 0; i < 4; i++) {
                x_bf[q * 4 + i][cA] = f2bf(xa[0][i] + b2v[0]);
                x_bf[q * 4 + i][cB] = f2bf(xa[1][i] + b2v[1]);
            }
        }
        __syncthreads();  // B3: x_bf ready; all sT reads done (rh alias safe)

        // ---- 4 Euler ODE substeps; r/z from registers, Ohh streamed ----
#pragma unroll 1
        for (int s = 0; s < 4; s++) {
            bf16x8 af[8];
#pragma unroll
            for (int k = 0; k < 8; k++) af[k] = *(const bf16x8*)&h_bf[tc][k * 32 + q * 8];
            f32x4 ar[2] = { Z4, Z4 }, az[2] = { Z4, Z4 };
#pragma unroll
            for (int nt = 0; nt < 2; nt++)
#pragma unroll
                for (int k = 0; k < 8; k++) {
                    ar[nt] = mfma16(af[k], wOr[nt * 8 + k], ar[nt]);
                    az[nt] = mfma16(af[k], wOz[nt * 8 + k], az[nt]);
                }
            float zs[2][4];
#pragma unroll
            for (int nt = 0; nt < 2; nt++)
#pragma unroll
                for (int i = 0; i < 4; i++) {
                    float rv = sigmoidf_(ar[nt][i]);
                    zs[nt][i] = sigmoidf_(az[nt][i]);
                    rh_bf[q * 4 + i][colbase + nt * 16] = f2bf(rv * hreg[nt][i]);
                }
            __syncthreads();  // B4: rh ready

            bf16x8 au[8];
#pragma unroll
            for (int k = 0; k < 8; k++) au[k] = *(const bf16x8*)&rh_bf[tc][k * 32 + q * 8];
            f32x4 uu[2] = { Z4, Z4 };
#pragma unroll
            for (int nt = 0; nt < 2; nt++)
#pragma unroll
                for (int ch = 0; ch < 2; ch++) {
                    bf16x8 v[4]; rd4(v);
#pragma unroll
                    for (int i = 0; i < 4; i++)
                        uu[nt] = mfma16(au[ch * 4 + i], v[i], uu[nt]);
                    pump();
                }
#pragma unroll
            for (int nt = 0; nt < 2; nt++)
#pragma unroll
                for (int i = 0; i < 4; i++) {
                    float hv = hreg[nt][i];
                    float hn = hv + 0.25f * (1.f - zs[nt][i]) * (tanhf_(uu[nt][i]) - hv);
                    hreg[nt][i] = hn;
                    h_bf[q * 4 + i][colbase + nt * 16] = f2bf(hn);
                }
            __syncthreads();  // B5: h ready for next phase
        }

        // ---- GRU cell: 24 chunks (Wih x-part then Whh h-part) ----
        f32x4 accr[2] = { Z4, Z4 }, accz[2] = { Z4, Z4 };
        f32x4 accxn[2] = { Z4, Z4 }, acchn[2] = { Z4, Z4 };
#pragma unroll
        for (int b = 0; b < 6; b++) {
            const int nt = b / 3, g = b - nt * 3;
            f32x4* tgt = (g == 0) ? &accr[nt] : (g == 1) ? &accz[nt] : &accxn[nt];
#pragma unroll
            for (int half = 0; half < 2; half++) {
                bf16x8 aw[4], v[4];
#pragma unroll
                for (int i = 0; i < 4; i++)
                    aw[i] = *(const bf16x8*)&x_bf[tc][(half * 4 + i) * 32 + q * 8];
                rd4(v);
#pragma unroll
                for (int i = 0; i < 4; i++) *tgt = mfma16(aw[i], v[i], *tgt);
                pump();
            }
        }
#pragma unroll
        for (int b = 0; b < 6; b++) {
            const int nt = b / 3, g = b - nt * 3;
            f32x4* tgt = (g == 0) ? &accr[nt] : (g == 1) ? &accz[nt] : &acchn[nt];
#pragma unroll
            for (int half = 0; half < 2; half++) {
                bf16x8 aw[4], v[4];
#pragma unroll
                for (int i = 0; i < 4; i++)
                    aw[i] = *(const bf16x8*)&h_bf[tc][(half * 4 + i) * 32 + q * 8];
                rd4(v);
#pragma unroll
                for (int i = 0; i < 4; i++) *tgt = mfma16(aw[i], v[i], *tgt);
                pump();
            }
        }
        __syncthreads();  // B6: all x_bf/h_bf reads done

#pragma unroll
        for (int nt = 0; nt < 2; nt++) {
            int col = colbase + nt * 16;
#pragma unroll
            for (int i = 0; i < 4; i++) {
                float rg = sigmoidf_(accr[nt][i] + rbv[nt]);
                float zg = sigmoidf_(accz[nt][i] + zbv[nt]);
                float ng = tanhf_(accxn[nt][i] + xnbv[nt] + rg * (acchn[nt][i] + hnbv[nt]));
                float hv = hreg[nt][i];
                float hn = (1.f - zg) * ng + zg * hv;
                hreg[nt][i] = hn;
                h_bf[q * 4 + i][col] = f2bf(hn);
            }
        }
        __syncthreads();  // B7: h_new ready

        // ---- output projection: 2 chunks (tail: no pumps left) ----
        {
            bf16x8 ap[8];
#pragma unroll
            for (int k = 0; k < 8; k++) ap[k] = *(const bf16x8*)&h_bf[tc][k * 32 + q * 8];
            f32x4 a = Z4;
            bf16x8 v[4];
            ring_wait<4>();
            {
                const ushort* sb = &ring[w][slot][0][0] + lo8;
#pragma unroll
                for (int i = 0; i < 4; i++) v[i] = *(const bf16x8*)(sb + i * 512);
                slot = (slot == 2) ? 0 : slot + 1;
#pragma unroll
                for (int i = 0; i < 4; i++) a = mfma16(ap[i], v[i], a);
            }
            ring_wait<0>();
            {
                const ushort* sb = &ring[w][slot][0][0] + lo8;
#pragma unroll
                for (int i = 0; i < 4; i++) v[i] = *(const bf16x8*)(sb + i * 512);
                slot = (slot == 2) ? 0 : slot + 1;
#pragma unroll
                for (int i = 0; i < 4; i++) a = mfma16(ap[4 + i], v[i], a);
            }
            int n = w * 16 + tc;
#pragma unroll
            for (int i = 0; i < 4; i++)
                out[(size_t)((m0 + q * 4 + i) * 128 + t) * 128 + n] = a[i] + brv;
        }
    }
}

// ---------------------------------------------------------------------------
// Launch.  Workspace: 1.64 MB fragment-packed bf16 weights (as round 5/6).
// ---------------------------------------------------------------------------
extern "C" void kernel_launch(void* const* d_in, const int* in_sizes, int n_in,
                              void* d_out, int out_size, void* d_ws, size_t ws_size,
                              hipStream_t stream) {
    const float* H   = (const float*)d_in[0];
    const float* W1  = (const float*)d_in[2];
    const float* b1  = (const float*)d_in[3];
    const float* W2  = (const float*)d_in[4];
    const float* b2  = (const float*)d_in[5];
    const float* Ohr = (const float*)d_in[6];
    const float* Ohz = (const float*)d_in[7];
    const float* Ohh = (const float*)d_in[8];
    const float* Wih = (const float*)d_in[9];
    const float* Whh = (const float*)d_in[10];
    const float* bih = (const float*)d_in[11];
    const float* bhh = (const float*)d_in[12];
    const float* Wr  = (const float*)d_in[13];
    const float* br  = (const float*)d_in[14];
    float* out = (float*)d_out;
    char* ws = (char*)d_ws;

    ushort* W1P  = (ushort*)(ws);
    ushort* W2P  = (ushort*)(ws + 131072);
    ushort* WrP  = (ushort*)(ws + 393216);
    ushort* OhrP = (ushort*)(ws + 458752);
    ushort* OhzP = (ushort*)(ws + 589824);
    ushort* OhhP = (ushort*)(ws + 720896);
    ushort* WihP = (ushort*)(ws + 851968);
    ushort* WhhP = (ushort*)(ws + 1245184);

    pack_trans_k<<<dim3(32),  256, 0, stream>>>(W1,  W1P, 512, 128);
    pack_trans_k<<<dim3(64),  256, 0, stream>>>(W2,  W2P, 256, 512);
    pack_trans_k<<<dim3(16),  256, 0, stream>>>(Wr,  WrP, 128, 256);
    pack_direct_k<<<dim3(32), 256, 0, stream>>>(Ohr, OhrP, 256, 256);
    pack_direct_k<<<dim3(32), 256, 0, stream>>>(Ohz, OhzP, 256, 256);
    pack_direct_k<<<dim3(32), 256, 0, stream>>>(Ohh, OhhP, 256, 256);
    pack_direct_k<<<dim3(96), 256, 0, stream>>>(Wih, WihP, 768, 256);
    pack_direct_k<<<dim3(96), 256, 0, stream>>>(Whh, WhhP, 768, 256);

    scan_fused<<<dim3(32), 512, 0, stream>>>(H, W1P, b1, W2P, b2,
                                             OhrP, OhzP, OhhP, WihP, WhhP,
                                             bih, bhh, WrP, br, out);
}

// Round 8
// 3036.100 us; speedup vs baseline: 2.6364x; 1.6008x over previous
//
#include <hip/hip_runtime.h>

typedef unsigned short ushort;
typedef unsigned int uint;
typedef __bf16 bf16x8 __attribute__((ext_vector_type(8)));
typedef ushort ushort8 __attribute__((ext_vector_type(8)));
typedef float f32x4 __attribute__((ext_vector_type(4)));

#define Z4 f32x4{0.f, 0.f, 0.f, 0.f}

__device__ __forceinline__ f32x4 mfma16(bf16x8 a, bf16x8 b, f32x4 c) {
    return __builtin_amdgcn_mfma_f32_16x16x32_bf16(a, b, c, 0, 0, 0);
}
__device__ __forceinline__ float bf2f(ushort h) {
    union { uint u; float f; } v; v.u = ((uint)h) << 16; return v.f;
}
__device__ __forceinline__ ushort f2bf(float f) {  // RNE
    union { float f; uint u; } v; v.f = f;
    uint u = v.u;
    uint r = (u + 0x7fffu + ((u >> 16) & 1u)) >> 16;
    return (ushort)r;
}
__device__ __forceinline__ float sigmoidf_(float x) { return 1.f / (1.f + __expf(-x)); }
__device__ __forceinline__ float tanhf_(float x) {
    float e = __expf(2.f * x);
    return 1.f - 2.f / (e + 1.f);
}

typedef __attribute__((address_space(1))) uint guint;
typedef __attribute__((address_space(3))) uint luint;
__device__ __forceinline__ void dma16(const ushort* g, ushort* l) {
    __builtin_amdgcn_global_load_lds((const guint*)g, (luint*)l, 16, 0, 0);
}
template <int N> __device__ __forceinline__ void ring_wait() {
    asm volatile("s_waitcnt vmcnt(%0)" ::"n"(N) : "memory");
}
// raw barrier: LDS ordering only — does NOT drain the per-wave DMA ring (vmcnt)
__device__ __forceinline__ void wg_sync() {
    asm volatile("s_waitcnt lgkmcnt(0)\n\ts_barrier" ::: "memory");
}

// ---------------------------------------------------------------------------
// Weight pre-pack, MFMA-B fragment-major: frag F = ntile*(K/32)+kf, 1 KB each.
// ---------------------------------------------------------------------------
__global__ void pack_direct_k(const float* __restrict__ src, ushort* __restrict__ dst,
                              int N, int K) {  // src row-major [N,K]
    int total = (N >> 4) * (K >> 5) * 64;
    int idx = blockIdx.x * 256 + threadIdx.x;
    if (idx >= total) return;
    int l = idx & 63, f = idx >> 6;
    int kfrags = K >> 5;
    int nt = f / kfrags, kf = f - nt * kfrags;
    int n = nt * 16 + (l & 15);
    int k0 = kf * 32 + (l >> 4) * 8;
    const float* s = src + (size_t)n * K + k0;
    ushort8 u;
#pragma unroll
    for (int j = 0; j < 8; j++) u[j] = f2bf(s[j]);
    *(ushort8*)&dst[(size_t)f * 512 + l * 8] = u;
}
__global__ void pack_trans_k(const float* __restrict__ src, ushort* __restrict__ dst,
                             int N, int K) {  // src row-major [K,N]
    int total = (N >> 4) * (K >> 5) * 64;
    int idx = blockIdx.x * 256 + threadIdx.x;
    if (idx >= total) return;
    int l = idx & 63, f = idx >> 6;
    int kfrags = K >> 5;
    int nt = f / kfrags, kf = f - nt * kfrags;
    int n = nt * 16 + (l & 15);
    int k0 = kf * 32 + (l >> 4) * 8;
    ushort8 u;
#pragma unroll
    for (int j = 0; j < 8; j++) u[j] = f2bf(src[(size_t)(k0 + j) * N + n]);
    *(ushort8*)&dst[(size_t)f * 512 + l * 8] = u;
}

// ---------------------------------------------------------------------------
// Fused MLP: X2 = relu(H@W1+b1)@W2+b2  -> bf16 [65536,256]
// 1024 blocks x 256 thr (4 waves); 64 rows/block; packed-B frags from global.
// ---------------------------------------------------------------------------
__global__ __launch_bounds__(256) void mlp_kernel(
    const float* __restrict__ H,     // [65536,128] fp32
    const ushort* __restrict__ W1P,  // packed N=512,K=128
    const float* __restrict__ b1,
    const ushort* __restrict__ W2P,  // packed N=256,K=512
    const float* __restrict__ b2,
    ushort* __restrict__ X2)         // [65536,256] bf16
{
    __shared__ __align__(16) ushort sH[64][136];
    __shared__ __align__(16) ushort sT[64][264];
    __shared__ float sb1[512], sb2[256];
    const int tid = threadIdx.x;
    const int w = tid >> 6, lane = tid & 63;
    const int q = lane >> 4, tc = lane & 15;
    const int lo8 = lane * 8;
    const int m0 = blockIdx.x * 64;

    {   // stage H 64x128 fp32 -> bf16
        int r = tid >> 2, c0 = (tid & 3) * 32;
        const float* src = H + (size_t)(m0 + r) * 128 + c0;
#pragma unroll
        for (int v = 0; v < 4; v++) {
            float4 a = *(const float4*)(src + v * 8);
            float4 b = *(const float4*)(src + v * 8 + 4);
            ushort8 u;
            u[0] = f2bf(a.x); u[1] = f2bf(a.y); u[2] = f2bf(a.z); u[3] = f2bf(a.w);
            u[4] = f2bf(b.x); u[5] = f2bf(b.y); u[6] = f2bf(b.z); u[7] = f2bf(b.w);
            *(ushort8*)&sH[r][c0 + v * 8] = u;
        }
    }
    for (int i = tid; i < 512; i += 256) sb1[i] = b1[i];
    if (tid < 256) sb2[tid] = b2[tid];
    __syncthreads();

    bf16x8 af[4];
#pragma unroll
    for (int kb = 0; kb < 4; kb++) af[kb] = *(const bf16x8*)&sH[w * 16 + tc][kb * 32 + q * 8];

    f32x4 accH[16];
#pragma unroll
    for (int nt = 0; nt < 16; nt++) accH[nt] = Z4;

#pragma unroll 1
    for (int half = 0; half < 2; half++) {
        __syncthreads();  // protect sT reuse across halves
#pragma unroll
        for (int j = 0; j < 16; j++) {
            int n = half * 256 + j * 16 + tc;
            const ushort* bp = W1P + (size_t)((half * 16 + j) * 4) * 512 + lo8;
            f32x4 a = Z4;
#pragma unroll
            for (int kb = 0; kb < 4; kb++)
                a = mfma16(af[kb], *(const bf16x8*)(bp + kb * 512), a);
            float bv = sb1[n];
#pragma unroll
            for (int i = 0; i < 4; i++)
                sT[w * 16 + q * 4 + i][j * 16 + tc] = f2bf(fmaxf(a[i] + bv, 0.f));
        }
        __syncthreads();

        bf16x8 a2[8];
#pragma unroll
        for (int kb = 0; kb < 8; kb++) a2[kb] = *(const bf16x8*)&sT[w * 16 + tc][kb * 32 + q * 8];
#pragma unroll
        for (int nt = 0; nt < 16; nt++) {
            const ushort* bp = W2P + (size_t)(nt * 16 + half * 8) * 512 + lo8;
#pragma unroll
            for (int kb = 0; kb < 8; kb++)
                accH[nt] = mfma16(a2[kb], *(const bf16x8*)(bp + kb * 512), accH[nt]);
        }
    }

#pragma unroll
    for (int nt = 0; nt < 16; nt++) {
        int col = nt * 16 + tc;
        float bv = sb2[col];
#pragma unroll
        for (int i = 0; i < 4; i++)
            X2[(size_t)(m0 + w * 16 + q * 4 + i) * 256 + col] = f2bf(accH[nt][i] + bv);
    }
}

// ---------------------------------------------------------------------------
// GEMM, packed-B: C = A @ B^T + bias.  A bf16 row-major [M,K], BP packed.
// mode 0: bf16 row-major out; 1: fp32 row-major out; 2: bf16 Xg-swizzle out
//   (swizzle: row=b*128+t -> dst[((b>>4)*128+t)*N + col]*16 + (b&15))
// ---------------------------------------------------------------------------
__global__ __launch_bounds__(256) void gemm128P(
    const ushort* __restrict__ A, const ushort* __restrict__ BP,
    const float* __restrict__ bias, void* __restrict__ Cout,
    int M, int N, int K, int mode)
{
    __shared__ __align__(16) ushort sA[128][40];
    const int tid = threadIdx.x;
    const int lane = tid & 63, wid = tid >> 6;
    const int q = lane >> 4, tc = lane & 15;
    const int lo8 = lane * 8;
    const int wm = (wid >> 1) * 64, wn = (wid & 1) * 64;
    const int bm = blockIdx.y * 128, bn = blockIdx.x * 128;

    f32x4 acc[4][4];
#pragma unroll
    for (int im = 0; im < 4; im++)
#pragma unroll
        for (int in_ = 0; in_ < 4; in_++) acc[im][in_] = Z4;

    const int arow = tid >> 1, acol = (tid & 1) * 16;
    const int kfrags = K >> 5;

    for (int kc = 0; kc < K; kc += 32) {
        const ushort* ga = A + (size_t)(bm + arow) * K + kc + acol;
        ushort8 va0 = *(const ushort8*)ga;
        ushort8 va1 = *(const ushort8*)(ga + 8);
        __syncthreads();
        *(ushort8*)&sA[arow][acol] = va0;
        *(ushort8*)&sA[arow][acol + 8] = va1;
        __syncthreads();

        bf16x8 af[4], bf[4];
#pragma unroll
        for (int im = 0; im < 4; im++) af[im] = *(const bf16x8*)&sA[wm + im * 16 + tc][q * 8];
#pragma unroll
        for (int in_ = 0; in_ < 4; in_++) {
            int nt = ((bn + wn) >> 4) + in_;
            bf[in_] = *(const bf16x8*)(BP + (size_t)(nt * kfrags + (kc >> 5)) * 512 + lo8);
        }
#pragma unroll
        for (int im = 0; im < 4; im++)
#pragma unroll
            for (int in_ = 0; in_ < 4; in_++)
                acc[im][in_] = mfma16(af[im], bf[in_], acc[im][in_]);
    }

#pragma unroll
    for (int in_ = 0; in_ < 4; in_++) {
        int col = bn + wn + in_ * 16 + tc;
        float bv = bias[col];
#pragma unroll
        for (int im = 0; im < 4; im++) {
            int row0 = bm + wm + im * 16 + q * 4;
#pragma unroll
            for (int r = 0; r < 4; r++) {
                float v = acc[im][in_][r] + bv;
                int row = row0 + r;
                if (mode == 0) {
                    ((ushort*)Cout)[(size_t)row * N + col] = f2bf(v);
                } else if (mode == 1) {
                    ((float*)Cout)[(size_t)row * N + col] = v;
                } else {
                    int b = row >> 7, t = row & 127;
                    size_t dst = (((size_t)(b >> 4) * 128 + t) * N + col) * 16 + (b & 15);
                    ((ushort*)Cout)[dst] = f2bf(v);
                }
            }
        }
    }
}

// ---------------------------------------------------------------------------
// Slim sequential scan: ODE (Or/Oz persistent VGPR, Ohh streamed) + GRU h-part
// (Whh streamed) only. x-gates precomputed (XgSw), h stored to hseq.
// 32 WGs x 512 thr; raw barriers (no vmcnt drain); per-wave DMA ring.
// Per-step ring chunks (4 frags = 4 KB each): 4 substeps x 4 (Ohh) + 12 (Whh)
// = 28 chunks.
// ---------------------------------------------------------------------------
__global__ __launch_bounds__(512, 2) void scan_fused(
    const ushort* __restrict__ XgSw,  // [32][128][768][16] bf16 swizzled
    const ushort* __restrict__ OhrP, const ushort* __restrict__ OhzP,
    const ushort* __restrict__ OhhP,  // packed N=256,K=256
    const ushort* __restrict__ WhhP,  // packed N=768,K=256
    const float*  __restrict__ bhh,   // [768]
    ushort* __restrict__ hseq)        // [65536,256] bf16, row = b*128+t
{
    const int m0 = blockIdx.x * 16;
    const int tid = threadIdx.x;
    const int w = tid >> 6, lane = tid & 63;
    const int q = lane >> 4, tc = lane & 15;
    const int lo8 = lane * 8;

    __shared__ __align__(16) ushort ring[8][3][2048];  // 96 KB
    __shared__ __align__(16) ushort h_bf[16][264];
    __shared__ __align__(16) ushort rh_bf[16][264];

    for (int i = tid; i < 16 * 264; i += 512) (&h_bf[0][0])[i] = 0;

    const int colbase = w * 32 + tc;
    const int cA = colbase, cB = colbase + 16;

    // biases (x-side bih already folded into Xg)
    float rbv[2]  = { bhh[cA], bhh[cB] };
    float zbv[2]  = { bhh[256 + cA], bhh[256 + cB] };
    float hnbv[2] = { bhh[512 + cA], bhh[512 + cB] };

    // persistent ODE r/z weights (2 ntiles x 8 kf each = 128 VGPRs)
    bf16x8 wOr[16], wOz[16];
#pragma unroll
    for (int f = 0; f < 16; f++) {
        wOr[f] = *(const bf16x8*)(OhrP + (size_t)(w * 16 + f) * 512 + lo8);
        wOz[f] = *(const bf16x8*)(OhzP + (size_t)(w * 16 + f) * 512 + lo8);
    }

    float hreg[2][4] = {{0.f, 0.f, 0.f, 0.f}, {0.f, 0.f, 0.f, 0.f}};

    __syncthreads();

#pragma unroll 1
    for (int t = 0; t < 128; t++) {
        // x-gate loads (consumed at GRU epilogue, after ring drained)
        const ushort* xgp = XgSw + (((size_t)blockIdx.x * 128 + t) * 768) * 16;
        uint2 xg[6];
#pragma unroll
        for (int g = 0; g < 3; g++)
#pragma unroll
            for (int nt = 0; nt < 2; nt++)
                xg[g * 2 + nt] =
                    *(const uint2*)(xgp + (size_t)(g * 256 + colbase + nt * 16) * 16 + q * 4);

        int ic = 0, islot = 0, slot = 0;
        auto pump = [&]() {
            if (ic >= 28) return;
            asm volatile("s_waitcnt lgkmcnt(0)" ::: "memory");
            const ushort* g;
            if (ic < 16) {  // Ohh: same 16-frag slice each substep
                g = OhhP + (size_t)(w * 16 + (ic & 3) * 4) * 512;
            } else {        // Whh: b-block = (ic-16)>>1, half = (ic-16)&1
                int gi = ic - 16, b = gi >> 1, half = gi & 1;
                int nt = b / 3, gg = b - nt * 3;
                g = WhhP + (size_t)(((gg * 16 + w * 2 + nt) * 8) + half * 4) * 512;
            }
            g += lo8;
            ushort* sb = &ring[w][islot][0];
            dma16(g, sb); dma16(g + 512, sb + 512);
            dma16(g + 1024, sb + 1024); dma16(g + 1536, sb + 1536);
            ic++; islot = (islot == 2) ? 0 : islot + 1;
        };
        auto rd4 = [&](bf16x8* v) {
            ring_wait<8>();
            const ushort* sb = &ring[w][slot][0] + lo8;
            v[0] = *(const bf16x8*)(sb);
            v[1] = *(const bf16x8*)(sb + 512);
            v[2] = *(const bf16x8*)(sb + 1024);
            v[3] = *(const bf16x8*)(sb + 1536);
            slot = (slot == 2) ? 0 : slot + 1;
        };
        pump(); pump(); pump();

        // ---- 4 Euler ODE substeps ----
#pragma unroll 1
        for (int s = 0; s < 4; s++) {
            bf16x8 af[8];
#pragma unroll
            for (int k = 0; k < 8; k++) af[k] = *(const bf16x8*)&h_bf[tc][k * 32 + q * 8];
            f32x4 ar[2] = { Z4, Z4 }, az[2] = { Z4, Z4 };
#pragma unroll
            for (int nt = 0; nt < 2; nt++)
#pragma unroll
                for (int k = 0; k < 8; k++) {
                    ar[nt] = mfma16(af[k], wOr[nt * 8 + k], ar[nt]);
                    az[nt] = mfma16(af[k], wOz[nt * 8 + k], az[nt]);
                }
            float zs[2][4];
#pragma unroll
            for (int nt = 0; nt < 2; nt++)
#pragma unroll
                for (int i = 0; i < 4; i++) {
                    float rv = sigmoidf_(ar[nt][i]);
                    zs[nt][i] = sigmoidf_(az[nt][i]);
                    rh_bf[q * 4 + i][colbase + nt * 16] = f2bf(rv * hreg[nt][i]);
                }
            wg_sync();  // rh ready

            bf16x8 au[8];
#pragma unroll
            for (int k = 0; k < 8; k++) au[k] = *(const bf16x8*)&rh_bf[tc][k * 32 + q * 8];
            f32x4 uu[2] = { Z4, Z4 };
#pragma unroll
            for (int c = 0; c < 4; c++) {  // chunk c: nt=c>>1, k-half=c&1
                bf16x8 v[4]; rd4(v);
#pragma unroll
                for (int j = 0; j < 4; j++)
                    uu[c >> 1] = mfma16(au[(c & 1) * 4 + j], v[j], uu[c >> 1]);
                pump();
            }
#pragma unroll
            for (int nt = 0; nt < 2; nt++)
#pragma unroll
                for (int i = 0; i < 4; i++) {
                    float hv = hreg[nt][i];
                    float hn = hv + 0.25f * (1.f - zs[nt][i]) * (tanhf_(uu[nt][i]) - hv);
                    hreg[nt][i] = hn;
                    h_bf[q * 4 + i][colbase + nt * 16] = f2bf(hn);
                }
            wg_sync();  // h ready
        }

        // ---- GRU h-part: Whh, 12 chunks ----
        bf16x8 ah[8];
#pragma unroll
        for (int k = 0; k < 8; k++) ah[k] = *(const bf16x8*)&h_bf[tc][k * 32 + q * 8];
        f32x4 accr[2] = { Z4, Z4 }, accz[2] = { Z4, Z4 }, accn[2] = { Z4, Z4 };
#pragma unroll
        for (int b = 0; b < 6; b++) {
            const int nt = b / 3, g = b - nt * 3;
            f32x4* tgt = (g == 0) ? &accr[nt] : (g == 1) ? &accz[nt] : &accn[nt];
#pragma unroll
            for (int half = 0; half < 2; half++) {
                bf16x8 v[4];
                if (b == 5 && half == 0) { ring_wait<4>(); }
                else if (b == 5 && half == 1) { ring_wait<0>(); }
                else { ring_wait<8>(); }
                {
                    const ushort* sb = &ring[w][slot][0] + lo8;
                    v[0] = *(const bf16x8*)(sb);
                    v[1] = *(const bf16x8*)(sb + 512);
                    v[2] = *(const bf16x8*)(sb + 1024);
                    v[3] = *(const bf16x8*)(sb + 1536);
                    slot = (slot == 2) ? 0 : slot + 1;
                }
#pragma unroll
                for (int j = 0; j < 4; j++)
                    *tgt = mfma16(ah[half * 4 + j], v[j], *tgt);
                pump();
            }
        }
        wg_sync();  // all h_bf reads done

        ring_wait<0>();  // xg (oldest vmem) definitely complete; ring empty
#pragma unroll
        for (int nt = 0; nt < 2; nt++) {
            int col = colbase + nt * 16;
#pragma unroll
            for (int i = 0; i < 4; i++) {
                uint2 ur = xg[0 + nt], uz = xg[2 + nt], un = xg[4 + nt];
                uint wr = (i < 2) ? ur.x : ur.y, wz = (i < 2) ? uz.x : uz.y,
                     wn = (i < 2) ? un.x : un.y;
                int sh = (i & 1) * 16;
                float xr = bf2f((ushort)(wr >> sh)), xz = bf2f((ushort)(wz >> sh)),
                      xn = bf2f((ushort)(wn >> sh));
                float rg = sigmoidf_(accr[nt][i] + xr + rbv[nt]);
                float zg = sigmoidf_(accz[nt][i] + xz + zbv[nt]);
                float ng = tanhf_(xn + rg * (accn[nt][i] + hnbv[nt]));
                float hv = hreg[nt][i];
                float hn = (1.f - zg) * ng + zg * hv;
                hreg[nt][i] = hn;
                h_bf[q * 4 + i][col] = f2bf(hn);
            }
        }
        wg_sync();  // h_new visible

        // ---- coalesced h store for the trailing projection GEMM ----
        {
            int row = tid >> 5, col = (tid & 31) * 8;
            ushort8 hv = *(const ushort8*)&h_bf[row][col];
            *(ushort8*)&hseq[((size_t)(m0 + row) * 128 + t) * 256 + col] = hv;
        }
    }
}

// ---------------------------------------------------------------------------
// Launch.  Workspace 129.6 MB:
//   [0, 100663296)            Xg swizzled [32][128][768][16] bf16
//   [100663296, 134217728)    X2 [65536,256] bf16  (aliased by hseq after use)
//   [134217728, ...)          packed weights (1.44 MB)
// ---------------------------------------------------------------------------
extern "C" void kernel_launch(void* const* d_in, const int* in_sizes, int n_in,
                              void* d_out, int out_size, void* d_ws, size_t ws_size,
                              hipStream_t stream) {
    const float* H   = (const float*)d_in[0];
    const float* W1  = (const float*)d_in[2];
    const float* b1  = (const float*)d_in[3];
    const float* W2  = (const float*)d_in[4];
    const float* b2  = (const float*)d_in[5];
    const float* Ohr = (const float*)d_in[6];
    const float* Ohz = (const float*)d_in[7];
    const float* Ohh = (const float*)d_in[8];
    const float* Wih = (const float*)d_in[9];
    const float* Whh = (const float*)d_in[10];
    const float* bih = (const float*)d_in[11];
    const float* bhh = (const float*)d_in[12];
    const float* Wr  = (const float*)d_in[13];
    const float* br  = (const float*)d_in[14];
    float* out = (float*)d_out;
    char* ws = (char*)d_ws;

    ushort* Xg   = (ushort*)(ws);
    ushort* X2   = (ushort*)(ws + 100663296);
    ushort* hseq = X2;  // alias: X2 dead before scan writes hseq
    char* pk = ws + 134217728;
    ushort* W1P  = (ushort*)(pk);
    ushort* W2P  = (ushort*)(pk + 131072);
    ushort* WrP  = (ushort*)(pk + 393216);
    ushort* OhrP = (ushort*)(pk + 458752);
    ushort* OhzP = (ushort*)(pk + 589824);
    ushort* OhhP = (ushort*)(pk + 720896);
    ushort* WihP = (ushort*)(pk + 851968);
    // end at +1245184

    pack_trans_k<<<dim3(32),  256, 0, stream>>>(W1,  W1P, 512, 128);
    pack_trans_k<<<dim3(64),  256, 0, stream>>>(W2,  W2P, 256, 512);
    pack_trans_k<<<dim3(16),  256, 0, stream>>>(Wr,  WrP, 128, 256);
    pack_direct_k<<<dim3(32), 256, 0, stream>>>(Ohr, OhrP, 256, 256);
    pack_direct_k<<<dim3(32), 256, 0, stream>>>(Ohz, OhzP, 256, 256);
    pack_direct_k<<<dim3(32), 256, 0, stream>>>(Ohh, OhhP, 256, 256);
    pack_direct_k<<<dim3(96), 256, 0, stream>>>(Wih, WihP, 768, 256);
    pack_direct_k<<<dim3(96), 256, 0, stream>>>(Whh, (ushort*)(pk + 1245184), 768, 256);
    ushort* WhhP = (ushort*)(pk + 1245184);

    // Phase A: X2 = MLP(H); Xg = X2 @ Wih^T + bih (swizzled for the scan)
    mlp_kernel<<<dim3(1024), 256, 0, stream>>>(H, W1P, b1, W2P, b2, X2);
    gemm128P<<<dim3(6, 512), 256, 0, stream>>>(X2, WihP, bih, Xg, 65536, 768, 256, 2);

    // Phase B: sequential scan -> hseq (aliases X2; X2 fully consumed above)
    scan_fused<<<dim3(32), 512, 0, stream>>>(Xg, OhrP, OhzP, OhhP, WhhP, bhh, hseq);

    // Phase C: out = hseq @ Wr + br (fp32)
    gemm128P<<<dim3(1, 512), 256, 0, stream>>>(hseq, WrP, br, out, 65536, 128, 256, 1);
}